// Round 2
// baseline (909.165 us; speedup 1.0000x reference)
//
#include <hip/hip_runtime.h>
#include <hip/hip_fp16.h>
#include <cstdint>
#include <cstddef>

typedef unsigned short u16t;
typedef __bf16 bf16x8 __attribute__((ext_vector_type(8)));
typedef float f32x4 __attribute__((ext_vector_type(4)));
typedef unsigned short u16x8 __attribute__((ext_vector_type(8)));

#define BT_ROWS 51200   // B*T
#define MODEL 512
#define FFNH 2048

__device__ __forceinline__ float bf2f(u16t u) {
  union { unsigned int i; float f; } v; v.i = ((unsigned int)u) << 16; return v.f;
}
__device__ __forceinline__ u16t f2bf(float f) {
  union { float f; unsigned int i; } v; v.f = f;
  return (u16t)((v.i + 0x7fffu + ((v.i >> 16) & 1u)) >> 16);
}
// dt: 0 = bf16, 1 = fp32, 2 = fp16
__device__ __forceinline__ float ldf(const void* p, size_t i, int dt) {
  if (dt == 1) return ((const float*)p)[i];
  u16t u = ((const u16t*)p)[i];
  if (dt == 0) return bf2f(u);
  __half h; *(u16t*)&h = u; return __half2float(h);
}
__device__ __forceinline__ void stf(void* p, size_t i, int dt, float f) {
  if (dt == 1) { ((float*)p)[i] = f; }
  else if (dt == 0) { ((u16t*)p)[i] = f2bf(f); }
  else { __half h = __float2half(f); ((u16t*)p)[i] = *(u16t*)&h; }
}
__device__ __forceinline__ void gl2lds16(const void* g, void* l) {
  __builtin_amdgcn_global_load_lds((const __attribute__((address_space(1))) void*)g,
                                   (__attribute__((address_space(3))) void*)l, 16, 0, 0);
}

// ---------------- dtype probe on w1: ONE block, no atomics ----------------
__global__ __launch_bounds__(256) void detect_dtype_k(const unsigned int* __restrict__ w1,
                                                      int* __restrict__ dflag) {
  __shared__ int sh[8];
  int a = 0, bc = 0;
  for (int it = 0; it < 64; it++) {
    unsigned int w = w1[it * 256 + threadIdx.x];
    u16t lo = (u16t)(w & 0xffffu), hi = (u16t)(w >> 16);
    float flo = bf2f(lo);
    a += (!(fabsf(flo) < 0.25f)) ? 1 : 0;
    __half hh; *(u16t*)&hh = hi; float fhi = __half2float(hh);
    bc += (fabsf(fhi) > 0.25f && fabsf(fhi) < 256.f) ? 1 : 0;
  }
#pragma unroll
  for (int o = 32; o; o >>= 1) { a += __shfl_xor(a, o); bc += __shfl_xor(bc, o); }
  int w = threadIdx.x >> 6;
  if ((threadIdx.x & 63) == 0) { sh[w] = a; sh[4 + w] = bc; }
  __syncthreads();
  if (threadIdx.x == 0) {
    int A = sh[0] + sh[1] + sh[2] + sh[3];
    int B = sh[4] + sh[5] + sh[6] + sh[7];
    dflag[0] = (A > 256) ? 1 : ((B < 256) ? 2 : 0);
  }
}

// ---------------- Mask layout probe ----------------
__global__ __launch_bounds__(256) void detect_mask_k(const unsigned int* __restrict__ msk,
                                                     int* __restrict__ flag) {
  int i = blockIdx.x * 256 + threadIdx.x;
  int bad = 0;
  if (i < 12800) bad = (msk[i] > 1u) ? 1 : 0;
  unsigned long long bl = __ballot(bad);
  if ((threadIdx.x & 63) == 0 && bl) atomicOr(flag, 1);
}

// ---------------- RMSNorm: one wave per row of 512, output bf16 ----------------
__global__ __launch_bounds__(256) void rmsnorm_k(const void* __restrict__ seq,
                                                 const void* __restrict__ w,
                                                 const int* __restrict__ dfp,
                                                 u16t* __restrict__ xn) {
  const int dt = dfp[0];
  int row = blockIdx.x * 4 + (threadIdx.x >> 6);
  int lane = threadIdx.x & 63;
  size_t base = (size_t)row * MODEL + lane * 8;
  float x[8]; float ss = 0.f;
  if (dt == 0) {
    u16x8 xv = *(const u16x8*)((const u16t*)seq + base);
#pragma unroll
    for (int j = 0; j < 8; j++) { x[j] = bf2f(xv[j]); ss += x[j] * x[j]; }
  } else if (dt == 1) {
    const f32x4* p = (const f32x4*)((const float*)seq + base);
    f32x4 va = p[0], vb = p[1];
#pragma unroll
    for (int j = 0; j < 4; j++) { x[j] = va[j]; x[4 + j] = vb[j]; }
#pragma unroll
    for (int j = 0; j < 8; j++) ss += x[j] * x[j];
  } else {
#pragma unroll
    for (int j = 0; j < 8; j++) { x[j] = ldf(seq, base + j, dt); ss += x[j] * x[j]; }
  }
#pragma unroll
  for (int o = 32; o; o >>= 1) ss += __shfl_xor(ss, o);
  float rstd = rsqrtf(ss * (1.f / 512.f) + 1.1920929e-07f);
  u16x8 ov;
#pragma unroll
  for (int j = 0; j < 8; j++) ov[j] = f2bf(x[j] * rstd * ldf(w, lane * 8 + j, dt));
  *(u16x8*)(xn + base) = ov;
}

// ---------------- Transpose (R x C) -> (C x R), bf16 out ----------------
// ih >= 0: interleave destination rows at 16-granularity: n -> (n>>4)*32 + ih*16 + (n&15)
__global__ __launch_bounds__(256) void transpose_k(const void* __restrict__ src,
                                                   u16t* __restrict__ dst,
                                                   const int* __restrict__ dfp,
                                                   int R, int C, int ih) {
  const int dt = dfp[0];
  __shared__ u16t tile[32][33];
  int x = threadIdx.x & 31, y = threadIdx.x >> 5;
  int c0 = blockIdx.x * 32, r0 = blockIdx.y * 32;
#pragma unroll
  for (int i = 0; i < 32; i += 8)
    tile[y + i][x] = f2bf(ldf(src, (size_t)(r0 + y + i) * C + c0 + x, dt));
  __syncthreads();
#pragma unroll
  for (int i = 0; i < 32; i += 8) {
    int n = c0 + y + i;
    int vr = (ih >= 0) ? (((n >> 4) << 5) + ih * 16 + (n & 15)) : n;
    dst[(size_t)vr * R + r0 + x] = tile[x][y + i];
  }
}

// ================= 256x256 GEMM core, 8 waves, dbuf LDS, 4 MFMA phases/K-tile ==========
// Fix vs r1: the whole NEXT K-tile is staged at phase 1 (its buffer has been free since
// the previous boundary) -> ~4 phases (~1000cy) of load lead time instead of ~1 phase.
// The boundary wait is a cheap vmcnt(0) (nothing newer in flight). No sched_barrier
// fences inside phases (m141); one at the boundary as WAR insurance across buffer swap.

#define MM16(afr, bfr, MHc, NHc)                                                    \
  do {                                                                              \
    __builtin_amdgcn_s_setprio(1);                                                  \
    _Pragma("unroll") for (int ks_ = 0; ks_ < 2; ks_++)                             \
        _Pragma("unroll") for (int mi_ = 0; mi_ < 4; mi_++)                         \
            _Pragma("unroll") for (int ni_ = 0; ni_ < 2; ni_++)                     \
                acc[(MHc)*4 + mi_][(NHc)*2 + ni_] =                                 \
                    __builtin_amdgcn_mfma_f32_16x16x32_bf16(                        \
                        afr[mi_][ks_], bfr[ni_][ks_],                               \
                        acc[(MHc)*4 + mi_][(NHc)*2 + ni_], 0, 0, 0);                \
    __builtin_amdgcn_s_setprio(0);                                                  \
  } while (0)

template <int K>
__device__ __forceinline__ void gemm256_core(const u16t* __restrict__ Ag,
                                             const u16t* __restrict__ Bg,
                                             u16t* __restrict__ As,
                                             u16t* __restrict__ Bs,
                                             f32x4 (&acc)[8][4]) {
  constexpr int NKT = K / 64;
  const int tid = threadIdx.x;
  const int lane = tid & 63;
  const int wave = tid >> 6;
  const int wr = wave >> 2, wc = wave & 3;
  const int quad = lane >> 4, l16 = lane & 15;
  const int wu = tid & ~63;

  // stage the ENTIRE K-tile s (A 32KB + B 32KB) into buffer (s&1)
  auto stageTile = [&](int s) {
    u16t* Ad = As + (s & 1) * 16384;
    u16t* Bd = Bs + (s & 1) * 16384;
#pragma unroll
    for (int c = 0; c < 4; c++) {
      int chunk = c * 512 + tid;
      int r = chunk >> 3;
      int k8 = (chunk & 7) ^ (r & 7);            // pre-swizzled source k-group
      gl2lds16(Ag + (size_t)r * K + s * 64 + k8 * 8, Ad + (size_t)(c * 512 + wu) * 8);
      gl2lds16(Bg + (size_t)r * K + s * 64 + k8 * 8, Bd + (size_t)(c * 512 + wu) * 8);
    }
  };
  auto lda = [&](bf16x8(&a)[4][2], int u, int MH) {
    const u16t* S = As + (u & 1) * 16384;
#pragma unroll
    for (int ks = 0; ks < 2; ks++)
#pragma unroll
      for (int mi = 0; mi < 4; mi++) {
        int row = wr * 128 + MH * 64 + mi * 16 + l16;
        int sw = (ks * 4 + quad) ^ (row & 7);
        a[mi][ks] = *(const bf16x8*)(S + row * 64 + sw * 8);
      }
  };
  auto ldb = [&](bf16x8(&b)[2][2], int u, int NH) {
    const u16t* S = Bs + (u & 1) * 16384;
#pragma unroll
    for (int ks = 0; ks < 2; ks++)
#pragma unroll
      for (int ni = 0; ni < 2; ni++) {
        int row = wc * 64 + NH * 32 + ni * 16 + l16;
        int sw = (ks * 4 + quad) ^ (row & 7);
        b[ni][ks] = *(const bf16x8*)(S + row * 64 + sw * 8);
      }
  };

  bf16x8 a[4][2], b0[2][2], b1[2][2];

  // prologue: tile 0
  stageTile(0);
  __builtin_amdgcn_sched_barrier(0);
  asm volatile("s_waitcnt vmcnt(0)" ::: "memory");
  __builtin_amdgcn_s_barrier();
  __builtin_amdgcn_sched_barrier(0);

  for (int u = 0; u < NKT; u++) {
    // phase 1: prefetch whole next tile, read (A-MH0, B-NH0), MFMA Q00
    if (u + 1 < NKT) stageTile(u + 1);
    lda(a, u, 0);
    ldb(b0, u, 0);
    __builtin_amdgcn_s_barrier();
    MM16(a, b0, 0, 0);
    __builtin_amdgcn_s_barrier();
    // phase 2: read B-NH1, MFMA Q01
    ldb(b1, u, 1);
    __builtin_amdgcn_s_barrier();
    MM16(a, b1, 0, 1);
    __builtin_amdgcn_s_barrier();
    // phase 3: read A-MH1, MFMA Q10
    lda(a, u, 1);
    __builtin_amdgcn_s_barrier();
    MM16(a, b0, 1, 0);
    __builtin_amdgcn_s_barrier();
    // phase 4: MFMA Q11 (register-only), then boundary
    MM16(a, b1, 1, 1);
    if (u + 1 < NKT) {
      __builtin_amdgcn_sched_barrier(0);
      asm volatile("s_waitcnt vmcnt(0)" ::: "memory");   // next tile fully landed (issued ~4 phases ago)
      __builtin_amdgcn_s_barrier();
      __builtin_amdgcn_sched_barrier(0);
    }
  }
}

// bijective XCD swizzle of linear block id (m204 variant)
__device__ __forceinline__ int xcd_swz(int o, int nwg) {
  int q = nwg >> 3, r = nwg & 7;
  int xcd = o & 7, i = o >> 3;
  return (xcd < r ? xcd * (q + 1) : r * (q + 1) + (xcd - r) * q) + i;
}

// ---------------- GEMM1: Act = silu(Xn@w1) * (Xn@w2), interleaved W12t (4096x512) ----------
__global__ __launch_bounds__(512, 2) void ffn_gemm1(const u16t* __restrict__ Xn,
                                                    const u16t* __restrict__ W12t,
                                                    u16t* __restrict__ Act) {
  __shared__ u16t As[2 * 16384];
  __shared__ u16t Bs[2 * 16384];
  const int tid = threadIdx.x;
  const int lane = tid & 63;
  const int wave = tid >> 6;
  const int wr = wave >> 2, wc = wave & 3;
  const int quad = lane >> 4, l16 = lane & 15;

  int o = blockIdx.y * 16 + blockIdx.x;
  int s = xcd_swz(o, gridDim.y * 16);
  int bx = s & 15, by = s >> 4;

  f32x4 acc[8][4];
  const f32x4 zf = {0.f, 0.f, 0.f, 0.f};
#pragma unroll
  for (int m = 0; m < 8; m++)
#pragma unroll
    for (int n = 0; n < 4; n++) acc[m][n] = zf;

  gemm256_core<512>(Xn + (size_t)by * 256 * 512, W12t + (size_t)bx * 256 * 512, As, Bs, acc);

  const int mBase = by * 256;
#pragma unroll
  for (int mi = 0; mi < 8; mi++)
#pragma unroll
    for (int p = 0; p < 2; p++)
#pragma unroll
      for (int r = 0; r < 4; r++) {
        int row = mBase + wr * 128 + mi * 16 + quad * 4 + r;
        int col = bx * 128 + (wc * 2 + p) * 16 + l16;
        float g1 = acc[mi][2 * p][r], g2 = acc[mi][2 * p + 1][r];
        float sl = g1 / (1.f + __expf(-g1));
        __builtin_nontemporal_store(f2bf(sl * g2), &Act[(size_t)row * FFNH + col]);
      }
}

// ---------------- GEMM2: H = Act@w3 + seq ----------------
__global__ __launch_bounds__(512, 2) void ffn_gemm2(const u16t* __restrict__ Act,
                                                    const u16t* __restrict__ W3t,
                                                    const void* __restrict__ Seq,
                                                    const int* __restrict__ dfp,
                                                    u16t* __restrict__ H, int rowOff) {
  __shared__ u16t As[2 * 16384];
  __shared__ u16t Bs[2 * 16384];
  const int dt = dfp[0];
  const int tid = threadIdx.x;
  const int lane = tid & 63;
  const int wave = tid >> 6;
  const int wr = wave >> 2, wc = wave & 3;
  const int quad = lane >> 4, l16 = lane & 15;

  int o = blockIdx.y * 2 + blockIdx.x;
  int s = xcd_swz(o, gridDim.y * 2);
  int bx = s & 1, by = s >> 1;

  f32x4 acc[8][4];
  const f32x4 zf = {0.f, 0.f, 0.f, 0.f};
#pragma unroll
  for (int m = 0; m < 8; m++)
#pragma unroll
    for (int n = 0; n < 4; n++) acc[m][n] = zf;

  gemm256_core<2048>(Act + (size_t)by * 256 * 2048, W3t + (size_t)bx * 256 * 2048, As, Bs, acc);

  const int mBase = by * 256;
#pragma unroll
  for (int mi = 0; mi < 8; mi++)
#pragma unroll
    for (int ni = 0; ni < 4; ni++)
#pragma unroll
      for (int r = 0; r < 4; r++) {
        int grow = rowOff + mBase + wr * 128 + mi * 16 + quad * 4 + r;
        int col = bx * 256 + wc * 64 + ni * 16 + l16;
        float v = acc[mi][ni][r] + ldf(Seq, (size_t)grow * MODEL + col, dt);
        __builtin_nontemporal_store(f2bf(v), &H[(size_t)grow * MODEL + col]);
      }
}

// ---------------- Attention: one block per (b, head), data-parallel phases ----------------
__global__ __launch_bounds__(256) void attn_k(const u16t* __restrict__ H,
                                              const void* __restrict__ q,
                                              const void* __restrict__ wk,
                                              const void* __restrict__ wv,
                                              const int* __restrict__ mask,
                                              const int* __restrict__ mflagp,
                                              const int* __restrict__ dfp,
                                              void* __restrict__ out) {
  const int b = blockIdx.x >> 3;
  const int n = blockIdx.x & 7;
  const int tid = threadIdx.x;
  const int w = tid >> 6;
  const int lane = tid & 63;
  const int T = 200;
  const int HS = 66;
  const int dt = dfp[0];
  const int mflag = mflagp[0];

  __shared__ u16t hbuf[200 * HS];
  __shared__ float qk[64];
  __shared__ float sc[200];
  __shared__ float part[256];
  __shared__ float red[8];
  __shared__ float ctx[64];

  for (int chunk = tid; chunk < 1600; chunk += 256) {
    int r = chunk >> 3, c = (chunk & 7) << 3;
    u16x8 v = *(const u16x8*)(H + (size_t)(b * 200 + r) * MODEL + n * 64 + c);
#pragma unroll
    for (int j = 0; j < 8; j++) hbuf[r * HS + c + j] = v[j];
  }

  {
    int d = tid >> 2, sub = tid & 3;
    float s = 0.f;
    size_t wb = ((size_t)n * 64 + d) * 64 + sub * 16;
    size_t qb = (size_t)(b * 8 + n) * 64 + sub * 16;
#pragma unroll
    for (int i = 0; i < 16; i++) s += ldf(wk, wb + i, dt) * ldf(q, qb + i, dt);
    part[tid] = s;
  }
  __syncthreads();
  if (tid < 64) qk[tid] = part[tid * 4] + part[tid * 4 + 1] + part[tid * 4 + 2] + part[tid * 4 + 3];
  __syncthreads();

  float sv = -INFINITY;
  if (tid < T) {
    float s = 0.f;
#pragma unroll 16
    for (int d = 0; d < 64; d++) s += bf2f(hbuf[tid * HS + d]) * qk[d];
    int mv = mflag ? (int)((const unsigned char*)mask)[b * 200 + tid] : mask[b * 200 + tid];
    sv = mv ? s * 0.125f : -INFINITY;
  }

  float mx = sv;
#pragma unroll
  for (int o = 32; o; o >>= 1) mx = fmaxf(mx, __shfl_xor(mx, o));
  if (lane == 0) red[w] = mx;
  __syncthreads();
  float gmax = fmaxf(fmaxf(red[0], red[1]), fmaxf(red[2], red[3]));
  float e = 0.f;
  if (gmax == -INFINITY) {
    if (tid == 0) e = 1.f;
  } else if (tid < T) {
    e = __expf(sv - gmax);
  }
  float s = e;
#pragma unroll
  for (int o = 32; o; o >>= 1) s += __shfl_xor(s, o);
  if (lane == 0) red[4 + w] = s;
  __syncthreads();
  float inv = 1.f / (red[4] + red[5] + red[6] + red[7]);
  if (tid < T) sc[tid] = e * inv;
  __syncthreads();

  float a2 = 0.f;
  for (int t = w; t < T; t += 4) a2 += sc[t] * bf2f(hbuf[t * HS + lane]);
  part[tid] = a2;
  __syncthreads();
  if (tid < 64) ctx[tid] = part[tid] + part[64 + tid] + part[128 + tid] + part[192 + tid];
  __syncthreads();

  {
    int od = tid & 63;
    float s2 = 0.f;
#pragma unroll
    for (int i = 0; i < 16; i++) {
      int d = w * 16 + i;
      s2 += ctx[d] * ldf(wv, ((size_t)n * 64 + d) * 64 + od, dt);
    }
    part[tid] = s2;
  }
  __syncthreads();
  if (tid < 64) {
    size_t oi = (size_t)(b * 8 + n) * 64 + tid;
    stf(out, oi, dt,
        part[tid] + part[64 + tid] + part[128 + tid] + part[192 + tid] + ldf(q, oi, dt));
  }
}

extern "C" void kernel_launch(void* const* d_in, const int* in_sizes, int n_in,
                              void* d_out, int out_size, void* d_ws, size_t ws_size,
                              hipStream_t stream) {
  (void)in_sizes; (void)n_in; (void)out_size;
  const void* q   = d_in[0];
  const void* seq = d_in[1];
  const void* rw  = d_in[2];
  const void* w1  = d_in[3];
  const void* w2  = d_in[4];
  const void* w3  = d_in[5];
  const void* wk  = d_in[6];
  const void* wv  = d_in[7];
  const int*  msk = (const int*)d_in[8];

  char* ws = (char*)d_ws;
  size_t off = 0;
  auto alloc = [&](size_t b) { void* p = ws + off; off = (off + b + 255) & ~(size_t)255; return p; };
  int*  flags = (int*)alloc(512);            // [0]=mflag, [4]=dflag
  int*  mflag = flags + 0;
  int*  dflag = flags + 4;
  u16t* Xn   = (u16t*)alloc((size_t)BT_ROWS * MODEL * 2);   // reused as H in-place per chunk
  u16t* W12t = (u16t*)alloc((size_t)2 * FFNH * MODEL * 2);  // interleaved w1^T/w2^T (4096x512)
  u16t* W3t  = (u16t*)alloc((size_t)MODEL * FFNH * 2);
  size_t actBytes = (ws_size > off) ? (ws_size - off) : 0;
  long ppc = (long)(actBytes / ((size_t)256 * FFNH * 2));   // 256-row panels per chunk
  if (ppc < 1) ppc = 1;
  if (ppc > 100) ppc = 100;   // 100 panels -> 105 MB Act chunk, L3-resident gemm1->gemm2
  u16t* ActB = (u16t*)(ws + off);

  hipMemsetAsync(flags, 0, 512, stream);
  detect_dtype_k<<<dim3(1), dim3(256), 0, stream>>>((const unsigned int*)w1, dflag);
  detect_mask_k<<<dim3(50), dim3(256), 0, stream>>>((const unsigned int*)msk, mflag);

  rmsnorm_k<<<dim3(BT_ROWS / 4), dim3(256), 0, stream>>>(seq, rw, dflag, Xn);
  // w1^T -> even 16-row groups, w2^T -> odd 16-row groups of W12t
  transpose_k<<<dim3(FFNH / 32, MODEL / 32), dim3(256), 0, stream>>>(w1, W12t, dflag, MODEL, FFNH, 0);
  transpose_k<<<dim3(FFNH / 32, MODEL / 32), dim3(256), 0, stream>>>(w2, W12t, dflag, MODEL, FFNH, 1);
  transpose_k<<<dim3(MODEL / 32, FFNH / 32), dim3(256), 0, stream>>>(w3, W3t, dflag, FFNH, MODEL, -1);

  for (int p0 = 0; p0 < 200; p0 += (int)ppc) {
    int panels = (200 - p0 < (int)ppc) ? (200 - p0) : (int)ppc;
    int rows0 = p0 * 256;
    ffn_gemm1<<<dim3(16, panels), dim3(512), 0, stream>>>(
        Xn + (size_t)rows0 * MODEL, W12t, ActB);
    ffn_gemm2<<<dim3(2, panels), dim3(512), 0, stream>>>(
        ActB, W3t, seq, dflag, Xn, rows0);
  }
  attn_k<<<dim3(2048), dim3(256), 0, stream>>>(Xn, q, wk, wv, msk, mflag, dflag, d_out);
}

// Round 3
// 738.552 us; speedup vs baseline: 1.2310x; 1.2310x over previous
//
#include <hip/hip_runtime.h>
#include <hip/hip_fp16.h>
#include <cstdint>
#include <cstddef>

typedef unsigned short u16t;
typedef __bf16 bf16x8 __attribute__((ext_vector_type(8)));
typedef float f32x4 __attribute__((ext_vector_type(4)));
typedef unsigned short u16x8 __attribute__((ext_vector_type(8)));

#define BT_ROWS 51200   // B*T
#define MODEL 512
#define FFNH 2048

__device__ __forceinline__ float bf2f(u16t u) {
  union { unsigned int i; float f; } v; v.i = ((unsigned int)u) << 16; return v.f;
}
__device__ __forceinline__ u16t f2bf(float f) {
  union { float f; unsigned int i; } v; v.f = f;
  return (u16t)((v.i + 0x7fffu + ((v.i >> 16) & 1u)) >> 16);
}
// dt: 0 = bf16, 1 = fp32, 2 = fp16
__device__ __forceinline__ float ldf(const void* p, size_t i, int dt) {
  if (dt == 1) return ((const float*)p)[i];
  u16t u = ((const u16t*)p)[i];
  if (dt == 0) return bf2f(u);
  __half h; *(u16t*)&h = u; return __half2float(h);
}
__device__ __forceinline__ void stf(void* p, size_t i, int dt, float f) {
  if (dt == 1) { ((float*)p)[i] = f; }
  else if (dt == 0) { ((u16t*)p)[i] = f2bf(f); }
  else { __half h = __float2half(f); ((u16t*)p)[i] = *(u16t*)&h; }
}
__device__ __forceinline__ void gl2lds16(const void* g, void* l) {
  __builtin_amdgcn_global_load_lds((const __attribute__((address_space(1))) void*)g,
                                   (__attribute__((address_space(3))) void*)l, 16, 0, 0);
}

// ---------------- dtype probe on w1: ONE block, no atomics ----------------
__global__ __launch_bounds__(256) void detect_dtype_k(const unsigned int* __restrict__ w1,
                                                      int* __restrict__ dflag) {
  __shared__ int sh[8];
  int a = 0, bc = 0;
  for (int it = 0; it < 64; it++) {
    unsigned int w = w1[it * 256 + threadIdx.x];
    u16t lo = (u16t)(w & 0xffffu), hi = (u16t)(w >> 16);
    float flo = bf2f(lo);
    a += (!(fabsf(flo) < 0.25f)) ? 1 : 0;
    __half hh; *(u16t*)&hh = hi; float fhi = __half2float(hh);
    bc += (fabsf(fhi) > 0.25f && fabsf(fhi) < 256.f) ? 1 : 0;
  }
#pragma unroll
  for (int o = 32; o; o >>= 1) { a += __shfl_xor(a, o); bc += __shfl_xor(bc, o); }
  int w = threadIdx.x >> 6;
  if ((threadIdx.x & 63) == 0) { sh[w] = a; sh[4 + w] = bc; }
  __syncthreads();
  if (threadIdx.x == 0) {
    int A = sh[0] + sh[1] + sh[2] + sh[3];
    int B = sh[4] + sh[5] + sh[6] + sh[7];
    dflag[0] = (A > 256) ? 1 : ((B < 256) ? 2 : 0);
  }
}

// ---------------- Mask layout probe ----------------
__global__ __launch_bounds__(256) void detect_mask_k(const unsigned int* __restrict__ msk,
                                                     int* __restrict__ flag) {
  int i = blockIdx.x * 256 + threadIdx.x;
  int bad = 0;
  if (i < 12800) bad = (msk[i] > 1u) ? 1 : 0;
  unsigned long long bl = __ballot(bad);
  if ((threadIdx.x & 63) == 0 && bl) atomicOr(flag, 1);
}

// ---------------- RMSNorm: one wave per row of 512, output bf16 ----------------
__global__ __launch_bounds__(256) void rmsnorm_k(const void* __restrict__ seq,
                                                 const void* __restrict__ w,
                                                 const int* __restrict__ dfp,
                                                 u16t* __restrict__ xn) {
  const int dt = dfp[0];
  int row = blockIdx.x * 4 + (threadIdx.x >> 6);
  int lane = threadIdx.x & 63;
  size_t base = (size_t)row * MODEL + lane * 8;
  float x[8]; float ss = 0.f;
  if (dt == 0) {
    u16x8 xv = *(const u16x8*)((const u16t*)seq + base);
#pragma unroll
    for (int j = 0; j < 8; j++) { x[j] = bf2f(xv[j]); ss += x[j] * x[j]; }
  } else if (dt == 1) {
    const f32x4* p = (const f32x4*)((const float*)seq + base);
    f32x4 va = p[0], vb = p[1];
#pragma unroll
    for (int j = 0; j < 4; j++) { x[j] = va[j]; x[4 + j] = vb[j]; }
#pragma unroll
    for (int j = 0; j < 8; j++) ss += x[j] * x[j];
  } else {
#pragma unroll
    for (int j = 0; j < 8; j++) { x[j] = ldf(seq, base + j, dt); ss += x[j] * x[j]; }
  }
#pragma unroll
  for (int o = 32; o; o >>= 1) ss += __shfl_xor(ss, o);
  float rstd = rsqrtf(ss * (1.f / 512.f) + 1.1920929e-07f);
  u16x8 ov;
#pragma unroll
  for (int j = 0; j < 8; j++) ov[j] = f2bf(x[j] * rstd * ldf(w, lane * 8 + j, dt));
  *(u16x8*)(xn + base) = ov;
}

// ---------------- Transpose (R x C) -> (C x R) with dtype conversion to bf16 ----------------
__global__ __launch_bounds__(256) void transpose_k(const void* __restrict__ src,
                                                   u16t* __restrict__ dst,
                                                   const int* __restrict__ dfp,
                                                   int R, int C) {
  const int dt = dfp[0];
  __shared__ u16t tile[32][33];
  int x = threadIdx.x & 31, y = threadIdx.x >> 5;
  int c0 = blockIdx.x * 32, r0 = blockIdx.y * 32;
#pragma unroll
  for (int i = 0; i < 32; i += 8)
    tile[y + i][x] = f2bf(ldf(src, (size_t)(r0 + y + i) * C + c0 + x, dt));
  __syncthreads();
#pragma unroll
  for (int i = 0; i < 32; i += 8) dst[(size_t)(c0 + y + i) * R + r0 + x] = tile[x][y + i];
}

// LDS K-group XOR swizzle: physical group = logical ^ (row & 7). 2-way banks (free).

// ---------------- GEMM1: Act = silu(Xn@w1) * (Xn@w2), BM=128 BN=64 BK=64 ----------------
// r0 structure (930 TF, 4 blocks/CU). New: LDS-transposed epilogue so Act stores are
// full-128B-line u16x8 (kills write-allocate FETCH of the 105MB Act stream).
__global__ __launch_bounds__(256, 4) void ffn_gemm1(const u16t* __restrict__ Xn,
                                                    const u16t* __restrict__ W1t,
                                                    const u16t* __restrict__ W2t,
                                                    u16t* __restrict__ Act) {
  __shared__ u16t shs[16384];            // 32KB: As | B1s | B2s, reused by epilogue
  u16t* As  = shs;                       // 128*64
  u16t* B1s = shs + 8192;                // 64*64
  u16t* B2s = shs + 12288;               // 64*64
  const int tid = threadIdx.x;
  const int lane = tid & 63;
  const int wave = tid >> 6;
  const int wr = wave >> 1, wc = wave & 1;
  const int quad = lane >> 4, l16 = lane & 15;
  const int nBase = blockIdx.x * 64;    // N-fastest for A-tile L2 locality
  const int mBase = blockIdx.y * 128;
  const int wuBase = tid & ~63;

  f32x4 acc1[4][2], acc2[4][2];
  const f32x4 zf = {0.f, 0.f, 0.f, 0.f};
#pragma unroll
  for (int i = 0; i < 4; i++)
#pragma unroll
    for (int j = 0; j < 2; j++) { acc1[i][j] = zf; acc2[i][j] = zf; }

  for (int kt = 0; kt < MODEL; kt += 64) {
#pragma unroll
    for (int c = 0; c < 4; c++) {
      int chunk = c * 256 + tid;
      int r = chunk >> 3, k8 = (chunk & 7) ^ (r & 7);   // swizzled source k-group
      gl2lds16(Xn + (size_t)(mBase + r) * MODEL + kt + k8 * 8, As + (size_t)(c * 256 + wuBase) * 8);
    }
#pragma unroll
    for (int c = 0; c < 2; c++) {
      int chunk = c * 256 + tid;
      int r = chunk >> 3, k8 = (chunk & 7) ^ (r & 7);
      gl2lds16(W1t + (size_t)(nBase + r) * MODEL + kt + k8 * 8, B1s + (size_t)(c * 256 + wuBase) * 8);
      gl2lds16(W2t + (size_t)(nBase + r) * MODEL + kt + k8 * 8, B2s + (size_t)(c * 256 + wuBase) * 8);
    }
    __syncthreads();
#pragma unroll
    for (int ks = 0; ks < 64; ks += 32) {
      bf16x8 a[4], b1[2], b2[2];
      const int sw = (ks >> 3) + quad;   // logical k-group
#pragma unroll
      for (int mi = 0; mi < 4; mi++) {
        int row = wr * 64 + mi * 16 + l16;
        a[mi] = *(const bf16x8*)(As + row * 64 + ((sw ^ (row & 7)) << 3));
      }
#pragma unroll
      for (int ni = 0; ni < 2; ni++) {
        int row = wc * 32 + ni * 16 + l16;
        b1[ni] = *(const bf16x8*)(B1s + row * 64 + ((sw ^ (row & 7)) << 3));
        b2[ni] = *(const bf16x8*)(B2s + row * 64 + ((sw ^ (row & 7)) << 3));
      }
#pragma unroll
      for (int mi = 0; mi < 4; mi++)
#pragma unroll
        for (int ni = 0; ni < 2; ni++) {
          acc1[mi][ni] = __builtin_amdgcn_mfma_f32_16x16x32_bf16(a[mi], b1[ni], acc1[mi][ni], 0, 0, 0);
          acc2[mi][ni] = __builtin_amdgcn_mfma_f32_16x16x32_bf16(a[mi], b2[ni], acc2[mi][ni], 0, 0, 0);
        }
    }
    __syncthreads();
  }
  // ---- epilogue: silu-gate -> LDS tile (stride 72) -> coalesced u16x8 stores ----
#pragma unroll
  for (int mi = 0; mi < 4; mi++)
#pragma unroll
    for (int ni = 0; ni < 2; ni++)
#pragma unroll
      for (int r = 0; r < 4; r++) {
        int rl = wr * 64 + mi * 16 + quad * 4 + r;      // 0..127
        int cl = wc * 32 + ni * 16 + l16;               // 0..63
        float g1 = acc1[mi][ni][r], g2 = acc2[mi][ni][r];
        float sl = g1 / (1.f + __expf(-g1));
        shs[rl * 72 + cl] = f2bf(sl * g2);
      }
  __syncthreads();
  {
    int row = tid >> 1, half = tid & 1;
    const u16t* sp = shs + row * 72 + half * 32;
    u16t* gp = Act + (size_t)(mBase + row) * FFNH + nBase + half * 32;
#pragma unroll
    for (int j = 0; j < 4; j++) *(u16x8*)(gp + j * 8) = *(const u16x8*)(sp + j * 8);
  }
}

// ---------------- GEMM2: H = Act@w3 + seq, BM=128 BN=256 BK=64 ----------------
// BN=256 halves the Act (A-side) logical re-read (MODEL/BN = 2 instead of 4) and
// improves staged-bytes/FLOP 1.37x. 4 waves, each computes all 128 rows x 64 cols.
__global__ __launch_bounds__(256, 2) void ffn_gemm2(const u16t* __restrict__ Act,
                                                    const u16t* __restrict__ W3t,
                                                    const void* __restrict__ Seq,
                                                    const int* __restrict__ dfp,
                                                    u16t* __restrict__ H, int rowOff) {
  __shared__ u16t As[128 * 64];   // 16KB
  __shared__ u16t Bs[256 * 64];   // 32KB
  const int dt = dfp[0];
  const int tid = threadIdx.x;
  const int lane = tid & 63;
  const int wc = tid >> 6;                 // wave 0..3 -> N strip
  const int quad = lane >> 4, l16 = lane & 15;
  const int nBase = blockIdx.x * 256;
  const int mBase = blockIdx.y * 128;
  const int wuBase = tid & ~63;

  f32x4 acc[8][4];
  const f32x4 zf = {0.f, 0.f, 0.f, 0.f};
#pragma unroll
  for (int i = 0; i < 8; i++)
#pragma unroll
    for (int j = 0; j < 4; j++) acc[i][j] = zf;

  for (int kt = 0; kt < FFNH; kt += 64) {
#pragma unroll
    for (int c = 0; c < 4; c++) {
      int chunk = c * 256 + tid;
      int r = chunk >> 3, k8 = (chunk & 7) ^ (r & 7);
      gl2lds16(Act + (size_t)(mBase + r) * FFNH + kt + k8 * 8, As + (size_t)(c * 256 + wuBase) * 8);
    }
#pragma unroll
    for (int c = 0; c < 8; c++) {
      int chunk = c * 256 + tid;
      int r = chunk >> 3, k8 = (chunk & 7) ^ (r & 7);
      gl2lds16(W3t + (size_t)(nBase + r) * FFNH + kt + k8 * 8, Bs + (size_t)(c * 256 + wuBase) * 8);
    }
    __syncthreads();
#pragma unroll
    for (int ks = 0; ks < 64; ks += 32) {
      bf16x8 a[8], b[4];
      const int sw = (ks >> 3) + quad;
#pragma unroll
      for (int mi = 0; mi < 8; mi++) {
        int row = mi * 16 + l16;
        a[mi] = *(const bf16x8*)(As + row * 64 + ((sw ^ (row & 7)) << 3));
      }
#pragma unroll
      for (int ni = 0; ni < 4; ni++) {
        int row = wc * 64 + ni * 16 + l16;
        b[ni] = *(const bf16x8*)(Bs + row * 64 + ((sw ^ (row & 7)) << 3));
      }
#pragma unroll
      for (int mi = 0; mi < 8; mi++)
#pragma unroll
        for (int ni = 0; ni < 4; ni++)
          acc[mi][ni] = __builtin_amdgcn_mfma_f32_16x16x32_bf16(a[mi], b[ni], acc[mi][ni], 0, 0, 0);
    }
    __syncthreads();
  }
#pragma unroll
  for (int mi = 0; mi < 8; mi++)
#pragma unroll
    for (int ni = 0; ni < 4; ni++)
#pragma unroll
      for (int r = 0; r < 4; r++) {
        int grow = rowOff + mBase + mi * 16 + quad * 4 + r;
        int col = nBase + wc * 64 + ni * 16 + l16;
        float v = acc[mi][ni][r] + ldf(Seq, (size_t)grow * MODEL + col, dt);
        H[(size_t)grow * MODEL + col] = f2bf(v);
      }
}

// ---------------- Attention: one block per (b, head), data-parallel phases ----------------
__global__ __launch_bounds__(256) void attn_k(const u16t* __restrict__ H,
                                              const void* __restrict__ q,
                                              const void* __restrict__ wk,
                                              const void* __restrict__ wv,
                                              const int* __restrict__ mask,
                                              const int* __restrict__ mflagp,
                                              const int* __restrict__ dfp,
                                              void* __restrict__ out) {
  const int b = blockIdx.x >> 3;
  const int n = blockIdx.x & 7;
  const int tid = threadIdx.x;
  const int w = tid >> 6;
  const int lane = tid & 63;
  const int T = 200;
  const int HS = 66;
  const int dt = dfp[0];
  const int mflag = mflagp[0];

  __shared__ u16t hbuf[200 * HS];   // 26.4 KB
  __shared__ float qk[64];
  __shared__ float sc[200];
  __shared__ float part[256];
  __shared__ float red[8];
  __shared__ float ctx[64];

  for (int chunk = tid; chunk < 1600; chunk += 256) {
    int r = chunk >> 3, c = (chunk & 7) << 3;
    u16x8 v = *(const u16x8*)(H + (size_t)(b * 200 + r) * MODEL + n * 64 + c);
#pragma unroll
    for (int j = 0; j < 8; j++) hbuf[r * HS + c + j] = v[j];
  }

  {
    int d = tid >> 2, sub = tid & 3;
    float s = 0.f;
    size_t wb = ((size_t)n * 64 + d) * 64 + sub * 16;
    size_t qb = (size_t)(b * 8 + n) * 64 + sub * 16;
#pragma unroll
    for (int i = 0; i < 16; i++) s += ldf(wk, wb + i, dt) * ldf(q, qb + i, dt);
    part[tid] = s;
  }
  __syncthreads();
  if (tid < 64) qk[tid] = part[tid * 4] + part[tid * 4 + 1] + part[tid * 4 + 2] + part[tid * 4 + 3];
  __syncthreads();

  float sv = -INFINITY;
  if (tid < T) {
    float s = 0.f;
#pragma unroll 16
    for (int d = 0; d < 64; d++) s += bf2f(hbuf[tid * HS + d]) * qk[d];
    int mv = mflag ? (int)((const unsigned char*)mask)[b * 200 + tid] : mask[b * 200 + tid];
    sv = mv ? s * 0.125f : -INFINITY;
  }

  float mx = sv;
#pragma unroll
  for (int o = 32; o; o >>= 1) mx = fmaxf(mx, __shfl_xor(mx, o));
  if (lane == 0) red[w] = mx;
  __syncthreads();
  float gmax = fmaxf(fmaxf(red[0], red[1]), fmaxf(red[2], red[3]));
  float e = 0.f;
  if (gmax == -INFINITY) {
    if (tid == 0) e = 1.f;              // NaN guard (reference guarantees mask[:,0]=True)
  } else if (tid < T) {
    e = __expf(sv - gmax);
  }
  float s = e;
#pragma unroll
  for (int o = 32; o; o >>= 1) s += __shfl_xor(s, o);
  if (lane == 0) red[4 + w] = s;
  __syncthreads();
  float inv = 1.f / (red[4] + red[5] + red[6] + red[7]);
  if (tid < T) sc[tid] = e * inv;
  __syncthreads();

  float a2 = 0.f;
  for (int t = w; t < T; t += 4) a2 += sc[t] * bf2f(hbuf[t * HS + lane]);
  part[tid] = a2;
  __syncthreads();
  if (tid < 64) ctx[tid] = part[tid] + part[64 + tid] + part[128 + tid] + part[192 + tid];
  __syncthreads();

  {
    int od = tid & 63;
    float s2 = 0.f;
#pragma unroll
    for (int i = 0; i < 16; i++) {
      int d = w * 16 + i;
      s2 += ctx[d] * ldf(wv, ((size_t)n * 64 + d) * 64 + od, dt);
    }
    part[tid] = s2;
  }
  __syncthreads();
  if (tid < 64) {
    size_t oi = (size_t)(b * 8 + n) * 64 + tid;
    stf(out, oi, dt,
        part[tid] + part[64 + tid] + part[128 + tid] + part[192 + tid] + ldf(q, oi, dt));
  }
}

extern "C" void kernel_launch(void* const* d_in, const int* in_sizes, int n_in,
                              void* d_out, int out_size, void* d_ws, size_t ws_size,
                              hipStream_t stream) {
  (void)in_sizes; (void)n_in; (void)out_size;
  const void* q   = d_in[0];
  const void* seq = d_in[1];
  const void* rw  = d_in[2];
  const void* w1  = d_in[3];
  const void* w2  = d_in[4];
  const void* w3  = d_in[5];
  const void* wk  = d_in[6];
  const void* wv  = d_in[7];
  const int*  msk = (const int*)d_in[8];

  char* ws = (char*)d_ws;
  size_t off = 0;
  auto alloc = [&](size_t b) { void* p = ws + off; off = (off + b + 255) & ~(size_t)255; return p; };
  int*  flags = (int*)alloc(512);            // [0]=mflag, [4]=dflag
  int*  mflag = flags + 0;
  int*  dflag = flags + 4;
  u16t* Xn  = (u16t*)alloc((size_t)BT_ROWS * MODEL * 2);   // reused as H in-place per chunk
  u16t* W1t = (u16t*)alloc((size_t)FFNH * MODEL * 2);
  u16t* W2t = (u16t*)alloc((size_t)FFNH * MODEL * 2);
  u16t* W3t = (u16t*)alloc((size_t)MODEL * FFNH * 2);
  size_t actBytes = (ws_size > off) ? (ws_size - off) : 0;
  long tpc = (long)(actBytes / ((size_t)128 * FFNH * 2));
  if (tpc < 1) tpc = 1;
  if (tpc > 200) tpc = 200;   // 200 tiles -> 105 MB Act chunk, L3-resident gemm1->gemm2
  u16t* ActB = (u16t*)(ws + off);

  hipMemsetAsync(flags, 0, 512, stream);
  detect_dtype_k<<<dim3(1), dim3(256), 0, stream>>>((const unsigned int*)w1, dflag);
  detect_mask_k<<<dim3(50), dim3(256), 0, stream>>>((const unsigned int*)msk, mflag);

  rmsnorm_k<<<dim3(BT_ROWS / 4), dim3(256), 0, stream>>>(seq, rw, dflag, Xn);
  transpose_k<<<dim3(FFNH / 32, MODEL / 32), dim3(256), 0, stream>>>(w1, W1t, dflag, MODEL, FFNH);
  transpose_k<<<dim3(FFNH / 32, MODEL / 32), dim3(256), 0, stream>>>(w2, W2t, dflag, MODEL, FFNH);
  transpose_k<<<dim3(MODEL / 32, FFNH / 32), dim3(256), 0, stream>>>(w3, W3t, dflag, FFNH, MODEL);

  for (int t0 = 0; t0 < 400; t0 += (int)tpc) {
    int tiles = (400 - t0 < (int)tpc) ? (400 - t0) : (int)tpc;
    int rows0 = t0 * 128;
    ffn_gemm1<<<dim3(FFNH / 64, tiles), dim3(256), 0, stream>>>(
        Xn + (size_t)rows0 * MODEL, W1t, W2t, ActB);
    ffn_gemm2<<<dim3(MODEL / 256, tiles), dim3(256), 0, stream>>>(
        ActB, W3t, seq, dflag, Xn, rows0);
  }
  attn_k<<<dim3(2048), dim3(256), 0, stream>>>(Xn, q, wk, wv, msk, mflag, dflag, d_out);
}

// Round 4
// 634.445 us; speedup vs baseline: 1.4330x; 1.1641x over previous
//
#include <hip/hip_runtime.h>
#include <hip/hip_fp16.h>
#include <cstdint>
#include <cstddef>

typedef unsigned short u16t;
typedef __bf16 bf16x8 __attribute__((ext_vector_type(8)));
typedef float f32x4 __attribute__((ext_vector_type(4)));
typedef unsigned short u16x8 __attribute__((ext_vector_type(8)));

#define BT_ROWS 51200   // B*T
#define MODEL 512
#define FFNH 2048

__device__ __forceinline__ float bf2f(u16t u) {
  union { unsigned int i; float f; } v; v.i = ((unsigned int)u) << 16; return v.f;
}
__device__ __forceinline__ u16t f2bf(float f) {
  union { float f; unsigned int i; } v; v.f = f;
  return (u16t)((v.i + 0x7fffu + ((v.i >> 16) & 1u)) >> 16);
}
// dt: 0 = bf16, 1 = fp32, 2 = fp16
__device__ __forceinline__ float ldf(const void* p, size_t i, int dt) {
  if (dt == 1) return ((const float*)p)[i];
  u16t u = ((const u16t*)p)[i];
  if (dt == 0) return bf2f(u);
  __half h; *(u16t*)&h = u; return __half2float(h);
}
__device__ __forceinline__ void stf(void* p, size_t i, int dt, float f) {
  if (dt == 1) { ((float*)p)[i] = f; }
  else if (dt == 0) { ((u16t*)p)[i] = f2bf(f); }
  else { __half h = __float2half(f); ((u16t*)p)[i] = *(u16t*)&h; }
}
__device__ __forceinline__ void gl2lds16(const void* g, void* l) {
  __builtin_amdgcn_global_load_lds((const __attribute__((address_space(1))) void*)g,
                                   (__attribute__((address_space(3))) void*)l, 16, 0, 0);
}

// ---- inline dtype probe: wave-ballot over 64 words of w1 (deterministic dataset) ----
// fp32: low u16 of each word = mantissa noise -> bf16-read often >=0.25 (A~32/64).
// bf16: hi u16 read-as-fp16 lands in (0.25,256) (B~64). fp16: neither fires.
__device__ __forceinline__ int detect_dt_inline(const unsigned int* __restrict__ w1p) {
  int lane = threadIdx.x & 63;
  unsigned int w = w1p[lane];
  u16t lo = (u16t)(w & 0xffffu), hi = (u16t)(w >> 16);
  float flo = bf2f(lo);
  __half hh; *(u16t*)&hh = hi; float fhi = __half2float(hh);
  int afire = (!(fabsf(flo) < 0.25f)) ? 1 : 0;
  int bfire = (fabsf(fhi) > 0.25f && fabsf(fhi) < 256.f) ? 1 : 0;
  int A = __popcll(__ballot(afire));
  int B = __popcll(__ballot(bfire));
  return (A > 16) ? 1 : ((B < 16) ? 2 : 0);
}

// ---- XCD partition swizzle: XCD k owns x in [(k&1)*NX/2, ...), y chunk (k>>1)*NY/4 ----
// Assumes linear-block-id % 8 == XCD (perf-only heuristic). Bijective when NX%2==0, NY%4==0.
__device__ __forceinline__ void swz_xy(int& bx, int& by, const int NX) {
  int NY = gridDim.y;
  if ((NY & 3) != 0) return;               // tail-safe: identity
  int lid = by * NX + bx;
  int k = lid & 7, j = lid >> 3;           // j in [0, NX*NY/8)
  const int hx = NX >> 1;
  bx = (k & 1) * hx + (j % hx);
  by = (k >> 1) * (NY >> 2) + (j / hx);
}

// ---------------- Mask layout probe: ONE block, no atomics, no memset ----------------
__global__ __launch_bounds__(256) void detect_mask_k(const unsigned int* __restrict__ msk,
                                                     int* __restrict__ flag) {
  __shared__ int sh[4];
  int bad = 0;
  for (int it = 0; it < 50; it++) bad |= (msk[it * 256 + threadIdx.x] > 1u) ? 1 : 0;
  unsigned long long bl = __ballot(bad);
  int w = threadIdx.x >> 6;
  if ((threadIdx.x & 63) == 0) sh[w] = (bl != 0ull) ? 1 : 0;
  __syncthreads();
  if (threadIdx.x == 0) flag[0] = sh[0] | sh[1] | sh[2] | sh[3];
}

// ---------------- RMSNorm: one wave per row of 512, output bf16 ----------------
__global__ __launch_bounds__(256) void rmsnorm_k(const void* __restrict__ seq,
                                                 const void* __restrict__ w,
                                                 const unsigned int* __restrict__ w1p,
                                                 u16t* __restrict__ xn) {
  const int dt = detect_dt_inline(w1p);
  int row = blockIdx.x * 4 + (threadIdx.x >> 6);
  int lane = threadIdx.x & 63;
  size_t base = (size_t)row * MODEL + lane * 8;
  float x[8]; float ss = 0.f;
  if (dt == 0) {
    u16x8 xv = *(const u16x8*)((const u16t*)seq + base);
#pragma unroll
    for (int j = 0; j < 8; j++) { x[j] = bf2f(xv[j]); ss += x[j] * x[j]; }
  } else if (dt == 1) {
    const f32x4* p = (const f32x4*)((const float*)seq + base);
    f32x4 va = p[0], vb = p[1];
#pragma unroll
    for (int j = 0; j < 4; j++) { x[j] = va[j]; x[4 + j] = vb[j]; }
#pragma unroll
    for (int j = 0; j < 8; j++) ss += x[j] * x[j];
  } else {
#pragma unroll
    for (int j = 0; j < 8; j++) { x[j] = ldf(seq, base + j, dt); ss += x[j] * x[j]; }
  }
#pragma unroll
  for (int o = 32; o; o >>= 1) ss += __shfl_xor(ss, o);
  float rstd = rsqrtf(ss * (1.f / 512.f) + 1.1920929e-07f);
  u16x8 ov;
#pragma unroll
  for (int j = 0; j < 8; j++) ov[j] = f2bf(x[j] * rstd * ldf(w, lane * 8 + j, dt));
  *(u16x8*)(xn + base) = ov;
}

// ---------------- Merged transpose: w1,w2,w3 -> W1t,W2t,W3t in one launch ----------------
__global__ __launch_bounds__(256) void transpose3_k(const void* __restrict__ w1,
                                                    const void* __restrict__ w2,
                                                    const void* __restrict__ w3,
                                                    u16t* __restrict__ W1t,
                                                    u16t* __restrict__ W2t,
                                                    u16t* __restrict__ W3t) {
  const int dt = detect_dt_inline((const unsigned int*)w1);
  __shared__ u16t tile[32][33];
  int bid = blockIdx.x;
  const void* src; u16t* dst; int R, C, bx, by;
  if (bid < 1024)      { src = w1; dst = W1t; R = MODEL; C = FFNH; bx = bid & 63; by = bid >> 6; }
  else if (bid < 2048) { int t = bid - 1024; src = w2; dst = W2t; R = MODEL; C = FFNH; bx = t & 63; by = t >> 6; }
  else                 { int t = bid - 2048; src = w3; dst = W3t; R = FFNH; C = MODEL; bx = t & 15; by = t >> 4; }
  int x = threadIdx.x & 31, y = threadIdx.x >> 5;
  int c0 = bx * 32, r0 = by * 32;
#pragma unroll
  for (int i = 0; i < 32; i += 8)
    tile[y + i][x] = f2bf(ldf(src, (size_t)(r0 + y + i) * C + c0 + x, dt));
  __syncthreads();
#pragma unroll
  for (int i = 0; i < 32; i += 8) dst[(size_t)(c0 + y + i) * R + r0 + x] = tile[x][y + i];
}

// LDS K-group XOR swizzle: physical group = logical ^ (row & 7). 2-way banks (free).

// ---------------- GEMM1: Act = silu(Xn@w1) * (Xn@w2), BM=128 BN=64 BK=64 ----------------
// r0 structure (930 TF, 4 blocks/CU) + XCD partition swizzle.
__global__ __launch_bounds__(256, 4) void ffn_gemm1(const u16t* __restrict__ Xn,
                                                    const u16t* __restrict__ W1t,
                                                    const u16t* __restrict__ W2t,
                                                    u16t* __restrict__ Act) {
  __shared__ u16t As[128 * 64];
  __shared__ u16t B1s[64 * 64];
  __shared__ u16t B2s[64 * 64];
  const int tid = threadIdx.x;
  const int lane = tid & 63;
  const int wave = tid >> 6;
  const int wr = wave >> 1, wc = wave & 1;
  const int quad = lane >> 4, l16 = lane & 15;
  int bx = blockIdx.x, by = blockIdx.y;
  swz_xy(bx, by, 32);                    // XCD k: 16 x-blocks (weights 2.1MB L2-resident) x NY/4 y
  const int nBase = bx * 64;
  const int mBase = by * 128;
  const int wuBase = tid & ~63;

  f32x4 acc1[4][2], acc2[4][2];
  const f32x4 zf = {0.f, 0.f, 0.f, 0.f};
#pragma unroll
  for (int i = 0; i < 4; i++)
#pragma unroll
    for (int j = 0; j < 2; j++) { acc1[i][j] = zf; acc2[i][j] = zf; }

  for (int kt = 0; kt < MODEL; kt += 64) {
#pragma unroll
    for (int c = 0; c < 4; c++) {
      int chunk = c * 256 + tid;
      int r = chunk >> 3, k8 = (chunk & 7) ^ (r & 7);   // swizzled source k-group
      gl2lds16(Xn + (size_t)(mBase + r) * MODEL + kt + k8 * 8, As + (size_t)(c * 256 + wuBase) * 8);
    }
#pragma unroll
    for (int c = 0; c < 2; c++) {
      int chunk = c * 256 + tid;
      int r = chunk >> 3, k8 = (chunk & 7) ^ (r & 7);
      gl2lds16(W1t + (size_t)(nBase + r) * MODEL + kt + k8 * 8, B1s + (size_t)(c * 256 + wuBase) * 8);
      gl2lds16(W2t + (size_t)(nBase + r) * MODEL + kt + k8 * 8, B2s + (size_t)(c * 256 + wuBase) * 8);
    }
    __syncthreads();
#pragma unroll
    for (int ks = 0; ks < 64; ks += 32) {
      bf16x8 a[4], b1[2], b2[2];
      const int sw = (ks >> 3) + quad;   // logical k-group
#pragma unroll
      for (int mi = 0; mi < 4; mi++) {
        int row = wr * 64 + mi * 16 + l16;
        a[mi] = *(const bf16x8*)(As + row * 64 + ((sw ^ (row & 7)) << 3));
      }
#pragma unroll
      for (int ni = 0; ni < 2; ni++) {
        int row = wc * 32 + ni * 16 + l16;
        b1[ni] = *(const bf16x8*)(B1s + row * 64 + ((sw ^ (row & 7)) << 3));
        b2[ni] = *(const bf16x8*)(B2s + row * 64 + ((sw ^ (row & 7)) << 3));
      }
#pragma unroll
      for (int mi = 0; mi < 4; mi++)
#pragma unroll
        for (int ni = 0; ni < 2; ni++) {
          acc1[mi][ni] = __builtin_amdgcn_mfma_f32_16x16x32_bf16(a[mi], b1[ni], acc1[mi][ni], 0, 0, 0);
          acc2[mi][ni] = __builtin_amdgcn_mfma_f32_16x16x32_bf16(a[mi], b2[ni], acc2[mi][ni], 0, 0, 0);
        }
    }
    __syncthreads();
  }
#pragma unroll
  for (int mi = 0; mi < 4; mi++)
#pragma unroll
    for (int ni = 0; ni < 2; ni++)
#pragma unroll
      for (int r = 0; r < 4; r++) {
        int row = mBase + wr * 64 + mi * 16 + quad * 4 + r;
        int col = nBase + wc * 32 + ni * 16 + l16;
        float g1 = acc1[mi][ni][r], g2 = acc2[mi][ni][r];
        float sl = g1 / (1.f + __expf(-g1));
        Act[(size_t)row * FFNH + col] = f2bf(sl * g2);
      }
}

// ---------------- GEMM2: H = Act@w3 + seq, BM=128 BN=128 BK=64 ----------------
__global__ __launch_bounds__(256, 4) void ffn_gemm2(const u16t* __restrict__ Act,
                                                    const u16t* __restrict__ W3t,
                                                    const void* __restrict__ Seq,
                                                    const unsigned int* __restrict__ w1p,
                                                    u16t* __restrict__ H, int rowOff) {
  __shared__ u16t As[128 * 64];
  __shared__ u16t Bs[128 * 64];
  const int dt = detect_dt_inline(w1p);
  const int tid = threadIdx.x;
  const int lane = tid & 63;
  const int wave = tid >> 6;
  const int wr = wave >> 1, wc = wave & 1;
  const int quad = lane >> 4, l16 = lane & 15;
  int bx = blockIdx.x, by = blockIdx.y;
  swz_xy(bx, by, 4);                     // XCD k: 2 x-blocks (W3t 1MB L2-resident) x NY/4 y
  const int nBase = bx * 128;
  const int mBase = by * 128;
  const int wuBase = tid & ~63;

  f32x4 acc[4][4];
  const f32x4 zf = {0.f, 0.f, 0.f, 0.f};
#pragma unroll
  for (int i = 0; i < 4; i++)
#pragma unroll
    for (int j = 0; j < 4; j++) acc[i][j] = zf;

  for (int kt = 0; kt < FFNH; kt += 64) {
#pragma unroll
    for (int c = 0; c < 4; c++) {
      int chunk = c * 256 + tid;
      int r = chunk >> 3, k8 = (chunk & 7) ^ (r & 7);
      gl2lds16(Act + (size_t)(mBase + r) * FFNH + kt + k8 * 8, As + (size_t)(c * 256 + wuBase) * 8);
      gl2lds16(W3t + (size_t)(nBase + r) * FFNH + kt + k8 * 8, Bs + (size_t)(c * 256 + wuBase) * 8);
    }
    __syncthreads();
#pragma unroll
    for (int ks = 0; ks < 64; ks += 32) {
      bf16x8 a[4], b[4];
      const int sw = (ks >> 3) + quad;
#pragma unroll
      for (int mi = 0; mi < 4; mi++) {
        int row = wr * 64 + mi * 16 + l16;
        a[mi] = *(const bf16x8*)(As + row * 64 + ((sw ^ (row & 7)) << 3));
      }
#pragma unroll
      for (int ni = 0; ni < 4; ni++) {
        int row = wc * 64 + ni * 16 + l16;
        b[ni] = *(const bf16x8*)(Bs + row * 64 + ((sw ^ (row & 7)) << 3));
      }
#pragma unroll
      for (int mi = 0; mi < 4; mi++)
#pragma unroll
        for (int ni = 0; ni < 4; ni++)
          acc[mi][ni] = __builtin_amdgcn_mfma_f32_16x16x32_bf16(a[mi], b[ni], acc[mi][ni], 0, 0, 0);
    }
    __syncthreads();
  }
#pragma unroll
  for (int mi = 0; mi < 4; mi++)
#pragma unroll
    for (int ni = 0; ni < 4; ni++)
#pragma unroll
      for (int r = 0; r < 4; r++) {
        int grow = rowOff + mBase + wr * 64 + mi * 16 + quad * 4 + r;
        int col = nBase + wc * 64 + ni * 16 + l16;
        float v = acc[mi][ni][r] + ldf(Seq, (size_t)grow * MODEL + col, dt);
        H[(size_t)grow * MODEL + col] = f2bf(v);
      }
}

// ---------------- Attention: one block per (b, head), data-parallel phases ----------------
// LDS row stride 66 u16 -> bank = (t + d/2) % 32 : 2-way in both read phases (free).
__global__ __launch_bounds__(256) void attn_k(const u16t* __restrict__ H,
                                              const void* __restrict__ q,
                                              const void* __restrict__ wk,
                                              const void* __restrict__ wv,
                                              const int* __restrict__ mask,
                                              const int* __restrict__ mflagp,
                                              const unsigned int* __restrict__ w1p,
                                              void* __restrict__ out) {
  const int b = blockIdx.x >> 3;
  const int n = blockIdx.x & 7;
  const int tid = threadIdx.x;
  const int w = tid >> 6;
  const int lane = tid & 63;
  const int T = 200;
  const int HS = 66;
  const int dt = detect_dt_inline(w1p);
  const int mflag = mflagp[0];

  __shared__ u16t hbuf[200 * HS];   // 26.4 KB
  __shared__ float qk[64];
  __shared__ float sc[200];
  __shared__ float part[256];
  __shared__ float red[8];
  __shared__ float ctx[64];

  // ---- stage H slice: coalesced u16x8 global reads, scalar LDS writes ----
  for (int chunk = tid; chunk < 1600; chunk += 256) {
    int r = chunk >> 3, c = (chunk & 7) << 3;
    u16x8 v = *(const u16x8*)(H + (size_t)(b * 200 + r) * MODEL + n * 64 + c);
#pragma unroll
    for (int j = 0; j < 8; j++) hbuf[r * HS + c + j] = v[j];
  }

  // ---- qk[d] = sum_e wk[n][d][e] * q[b][n][e] ; 4 threads per output d ----
  {
    int d = tid >> 2, sub = tid & 3;
    float s = 0.f;
    size_t wb = ((size_t)n * 64 + d) * 64 + sub * 16;
    size_t qb = (size_t)(b * 8 + n) * 64 + sub * 16;
#pragma unroll
    for (int i = 0; i < 16; i++) s += ldf(wk, wb + i, dt) * ldf(q, qb + i, dt);
    part[tid] = s;
  }
  __syncthreads();
  if (tid < 64) qk[tid] = part[tid * 4] + part[tid * 4 + 1] + part[tid * 4 + 2] + part[tid * 4 + 3];
  __syncthreads();

  // ---- scores: thread t does 64 LDS FMAs (qk[] is broadcast) ----
  float sv = -INFINITY;
  if (tid < T) {
    float s = 0.f;
#pragma unroll 16
    for (int d = 0; d < 64; d++) s += bf2f(hbuf[tid * HS + d]) * qk[d];
    int mv = mflag ? (int)((const unsigned char*)mask)[b * 200 + tid] : mask[b * 200 + tid];
    sv = mv ? s * 0.125f : -INFINITY;
  }

  // ---- softmax over T ----
  float mx = sv;
#pragma unroll
  for (int o = 32; o; o >>= 1) mx = fmaxf(mx, __shfl_xor(mx, o));
  if (lane == 0) red[w] = mx;
  __syncthreads();
  float gmax = fmaxf(fmaxf(red[0], red[1]), fmaxf(red[2], red[3]));
  float e = 0.f;
  if (gmax == -INFINITY) {
    if (tid == 0) e = 1.f;              // NaN guard (reference guarantees mask[:,0]=True)
  } else if (tid < T) {
    e = __expf(sv - gmax);
  }
  float s = e;
#pragma unroll
  for (int o = 32; o; o >>= 1) s += __shfl_xor(s, o);
  if (lane == 0) red[4 + w] = s;
  __syncthreads();
  float inv = 1.f / (red[4] + red[5] + red[6] + red[7]);
  if (tid < T) sc[tid] = e * inv;
  __syncthreads();

  // ---- ctx[d] = sum_t p[t] * h[t][d] ; wave w covers t = w::4 ----
  float a2 = 0.f;
  for (int t = w; t < T; t += 4) a2 += sc[t] * bf2f(hbuf[t * HS + lane]);
  part[tid] = a2;
  __syncthreads();
  if (tid < 64) ctx[tid] = part[tid] + part[64 + tid] + part[128 + tid] + part[192 + tid];
  __syncthreads();

  // ---- out = ctx @ wv + q ; wave w covers d = w*16..w*16+15 ----
  {
    int od = tid & 63;
    float s2 = 0.f;
#pragma unroll
    for (int i = 0; i < 16; i++) {
      int d = w * 16 + i;
      s2 += ctx[d] * ldf(wv, ((size_t)n * 64 + d) * 64 + od, dt);
    }
    part[tid] = s2;
  }
  __syncthreads();
  if (tid < 64) {
    size_t oi = (size_t)(b * 8 + n) * 64 + tid;
    stf(out, oi, dt,
        part[tid] + part[64 + tid] + part[128 + tid] + part[192 + tid] + ldf(q, oi, dt));
  }
}

extern "C" void kernel_launch(void* const* d_in, const int* in_sizes, int n_in,
                              void* d_out, int out_size, void* d_ws, size_t ws_size,
                              hipStream_t stream) {
  (void)in_sizes; (void)n_in; (void)out_size;
  const void* q   = d_in[0];
  const void* seq = d_in[1];
  const void* rw  = d_in[2];
  const void* w1  = d_in[3];
  const void* w2  = d_in[4];
  const void* w3  = d_in[5];
  const void* wk  = d_in[6];
  const void* wv  = d_in[7];
  const int*  msk = (const int*)d_in[8];

  char* ws = (char*)d_ws;
  size_t off = 0;
  auto alloc = [&](size_t b) { void* p = ws + off; off = (off + b + 255) & ~(size_t)255; return p; };
  int*  flags = (int*)alloc(512);            // [0]=mflag
  int*  mflag = flags + 0;
  u16t* Xn  = (u16t*)alloc((size_t)BT_ROWS * MODEL * 2);   // reused as H in-place per chunk
  u16t* W1t = (u16t*)alloc((size_t)FFNH * MODEL * 2);
  u16t* W2t = (u16t*)alloc((size_t)FFNH * MODEL * 2);
  u16t* W3t = (u16t*)alloc((size_t)MODEL * FFNH * 2);
  size_t actBytes = (ws_size > off) ? (ws_size - off) : 0;
  long tpc = (long)(actBytes / ((size_t)128 * FFNH * 2));
  if (tpc < 1) tpc = 1;
  if (tpc > 200) tpc = 200;   // 200 tiles -> 105 MB Act chunk, L3-resident gemm1->gemm2
  u16t* ActB = (u16t*)(ws + off);

  // mask probe (1 block) overlaps rmsnorm; dtype probing is inline per consumer block.
  detect_mask_k<<<dim3(1), dim3(256), 0, stream>>>((const unsigned int*)msk, mflag);
  rmsnorm_k<<<dim3(BT_ROWS / 4), dim3(256), 0, stream>>>(seq, rw, (const unsigned int*)w1, Xn);
  transpose3_k<<<dim3(3072), dim3(256), 0, stream>>>(w1, w2, w3, W1t, W2t, W3t);

  for (int t0 = 0; t0 < 400; t0 += (int)tpc) {
    int tiles = (400 - t0 < (int)tpc) ? (400 - t0) : (int)tpc;
    int rows0 = t0 * 128;
    ffn_gemm1<<<dim3(FFNH / 64, tiles), dim3(256), 0, stream>>>(
        Xn + (size_t)rows0 * MODEL, W1t, W2t, ActB);
    ffn_gemm2<<<dim3(MODEL / 128, tiles), dim3(256), 0, stream>>>(
        ActB, W3t, seq, (const unsigned int*)w1, Xn, rows0);
  }
  attn_k<<<dim3(2048), dim3(256), 0, stream>>>(Xn, q, wk, wv, msk, mflag,
                                               (const unsigned int*)w1, d_out);
}